// Round 1
// baseline (69.811 us; speedup 1.0000x reference)
//
#include <hip/hip_runtime.h>
#include <hip/hip_bf16.h>

// SOM layer: out[b] = mean_p ||x_b - proto_p||^2
//          = ||x_b||^2 + (1/P)*sum_p||p||^2 - (2/P)*dot(x_b, colsum)
// B=8192, P=1024, D=256, all fp32.
//
// ws layout (floats): ws[0..255] = colsum[d], ws[256] = sum(proto^2)

#define SOM_B 8192
#define SOM_P 1024
#define SOM_D 256

// ---- Kernel A: reduce prototypes into ws (grid=16 blocks x 256 thr) ----
// Each block handles 64 rows of P; 4 waves/block, 16 rows/wave.
// Lane l owns float4 column l (cols 4l..4l+3). Coalesced 16B loads.
__global__ __launch_bounds__(256) void som_proto_reduce(
    const float* __restrict__ proto, float* __restrict__ ws) {
    const int lane = threadIdx.x & 63;
    const int wv   = threadIdx.x >> 6;                 // 0..3
    const int row0 = blockIdx.x * 64 + wv * 16;
    const float4* p4 = (const float4*)proto;           // row stride = 64 float4

    float4 cs = {0.f, 0.f, 0.f, 0.f};
    float sq = 0.f;
#pragma unroll
    for (int i = 0; i < 16; ++i) {
        float4 v = p4[(size_t)(row0 + i) * (SOM_D / 4) + lane];
        cs.x += v.x; cs.y += v.y; cs.z += v.z; cs.w += v.w;
        sq   += v.x * v.x + v.y * v.y + v.z * v.z + v.w * v.w;
    }
    // column sums: 16 blocks x 4 waves contend per address -> 64-way, tiny.
    atomicAdd(&ws[lane * 4 + 0], cs.x);
    atomicAdd(&ws[lane * 4 + 1], cs.y);
    atomicAdd(&ws[lane * 4 + 2], cs.z);
    atomicAdd(&ws[lane * 4 + 3], cs.w);
    // wave-reduce the squared sum, one atomic per wave
#pragma unroll
    for (int off = 32; off; off >>= 1) sq += __shfl_down(sq, off, 64);
    if (lane == 0) atomicAdd(&ws[SOM_D], sq);
}

// ---- Kernel B: per-row output (grid=2048 blocks x 256 thr) ----
// One wave per row of x. Lane l loads float4 of the row (64*4=256 cols).
__global__ __launch_bounds__(256) void som_out_kernel(
    const float* __restrict__ x, const float* __restrict__ ws,
    float* __restrict__ out) {
    const int lane = threadIdx.x & 63;
    const int wv   = threadIdx.x >> 6;                 // 0..3
    const int row  = blockIdx.x * 4 + wv;

    const float4 xv = ((const float4*)(x + (size_t)row * SOM_D))[lane];
    const float4 mv = ((const float4*)ws)[lane];       // colsum, L1-broadcast

    float sq = xv.x * xv.x + xv.y * xv.y + xv.z * xv.z + xv.w * xv.w;
    float dt = xv.x * mv.x + xv.y * mv.y + xv.z * mv.z + xv.w * mv.w;
#pragma unroll
    for (int off = 32; off; off >>= 1) {
        sq += __shfl_down(sq, off, 64);
        dt += __shfl_down(dt, off, 64);
    }
    if (lane == 0) {
        const float invP = 1.0f / (float)SOM_P;
        out[row] = sq + (ws[SOM_D] - 2.0f * dt) * invP;
    }
}

extern "C" void kernel_launch(void* const* d_in, const int* in_sizes, int n_in,
                              void* d_out, int out_size, void* d_ws, size_t ws_size,
                              hipStream_t stream) {
    const float* x     = (const float*)d_in[0];   // (B, D) fp32
    const float* proto = (const float*)d_in[1];   // (P, D) fp32
    float* out = (float*)d_out;                   // (B,)  fp32
    float* ws  = (float*)d_ws;                    // >= 257 floats

    // zero the reduction workspace (ws is re-poisoned 0xAA before each call)
    hipMemsetAsync(ws, 0, (SOM_D + 1) * sizeof(float), stream);

    som_proto_reduce<<<SOM_P / 64, 256, 0, stream>>>(proto, ws);
    som_out_kernel<<<SOM_B / 4, 256, 0, stream>>>(x, ws, out);
}

// Round 2
// 62.846 us; speedup vs baseline: 1.1108x; 1.1108x over previous
//
#include <hip/hip_runtime.h>
#include <hip/hip_bf16.h>

// SOM layer: out[b] = mean_p ||x_b - proto_p||^2
//          = ||x_b||^2 + (1/P)*sum_p||p||^2 - (2/P)*dot(x_b, colsum)
// B=8192, P=1024, D=256, all fp32.
//
// ws layout (floats):
//   ws[g*256 + d]  (g=0..15) : block g's partial colsum over its 64 proto rows
//   ws[4096 + g]             : block g's partial sum(proto^2)
// No memset needed: kernel A overwrites every slot it owns (deterministic,
// no atomics), kernel B reduces the 16 partials.

#define SOM_B 8192
#define SOM_P 1024
#define SOM_D 256
#define NPART 16

// ---- Kernel A: per-block prototype partials (grid=16 x 256 thr) ----
// Block g handles 64 rows; 4 waves x 16 rows; lane owns float4 column lane.
__global__ __launch_bounds__(256) void som_proto_partial(
    const float* __restrict__ proto, float* __restrict__ ws) {
    const int lane = threadIdx.x & 63;
    const int wv   = threadIdx.x >> 6;                 // 0..3
    const int row0 = blockIdx.x * 64 + wv * 16;
    const float4* p4 = (const float4*)proto;           // row stride 64 float4

    float4 cs = {0.f, 0.f, 0.f, 0.f};
    float sq = 0.f;
#pragma unroll
    for (int i = 0; i < 16; ++i) {
        float4 v = p4[(size_t)(row0 + i) * (SOM_D / 4) + lane];
        cs.x += v.x; cs.y += v.y; cs.z += v.z; cs.w += v.w;
        sq   += v.x * v.x + v.y * v.y + v.z * v.z + v.w * v.w;
    }
    __shared__ float4 lds_cs[4][64];
    __shared__ float  lds_sq[4];
#pragma unroll
    for (int off = 32; off; off >>= 1) sq += __shfl_down(sq, off, 64);
    if (lane == 0) lds_sq[wv] = sq;
    lds_cs[wv][lane] = cs;
    __syncthreads();
    if (threadIdx.x < 64) {
        float4 a = lds_cs[0][lane], b = lds_cs[1][lane];
        float4 c = lds_cs[2][lane], d = lds_cs[3][lane];
        float4 t;
        t.x = (a.x + b.x) + (c.x + d.x);
        t.y = (a.y + b.y) + (c.y + d.y);
        t.z = (a.z + b.z) + (c.z + d.z);
        t.w = (a.w + b.w) + (c.w + d.w);
        ((float4*)(ws + (size_t)blockIdx.x * SOM_D))[lane] = t;
        if (lane == 0)
            ws[NPART * SOM_D + blockIdx.x] =
                (lds_sq[0] + lds_sq[1]) + (lds_sq[2] + lds_sq[3]);
    }
}

// ---- Kernel B: reduce partials + per-row output (grid=2048 x 256 thr) ----
__global__ __launch_bounds__(256) void som_out_kernel(
    const float* __restrict__ x, const float* __restrict__ ws,
    float* __restrict__ out) {
    __shared__ float4 cs4[SOM_D / 4];
    __shared__ float  sqp_lds;
    const int t = threadIdx.x;

    float c = 0.f;
#pragma unroll
    for (int g = 0; g < NPART; ++g) c += ws[g * SOM_D + t];   // L2-hot, coalesced
    ((float*)cs4)[t] = c;
    if (t == 0) {
        float s = 0.f;
#pragma unroll
        for (int g = 0; g < NPART; ++g) s += ws[NPART * SOM_D + g];
        sqp_lds = s;
    }
    __syncthreads();

    const int lane = t & 63;
    const int wv   = t >> 6;
    const int row  = blockIdx.x * 4 + wv;

    const float4 xv = ((const float4*)(x + (size_t)row * SOM_D))[lane];
    const float4 mv = cs4[lane];                       // ds_read_b128, 2-way free

    float sq = xv.x * xv.x + xv.y * xv.y + xv.z * xv.z + xv.w * xv.w;
    float dt = xv.x * mv.x + xv.y * mv.y + xv.z * mv.z + xv.w * mv.w;
#pragma unroll
    for (int off = 32; off; off >>= 1) {
        sq += __shfl_down(sq, off, 64);
        dt += __shfl_down(dt, off, 64);
    }
    if (lane == 0) {
        const float invP = 1.0f / (float)SOM_P;
        out[row] = sq + (sqp_lds - 2.0f * dt) * invP;
    }
}

extern "C" void kernel_launch(void* const* d_in, const int* in_sizes, int n_in,
                              void* d_out, int out_size, void* d_ws, size_t ws_size,
                              hipStream_t stream) {
    const float* x     = (const float*)d_in[0];   // (B, D) fp32
    const float* proto = (const float*)d_in[1];   // (P, D) fp32
    float* out = (float*)d_out;                   // (B,)  fp32
    float* ws  = (float*)d_ws;                    // partials

    som_proto_partial<<<NPART, 256, 0, stream>>>(proto, ws);
    som_out_kernel<<<SOM_B / 4, 256, 0, stream>>>(x, ws, out);
}